// Round 4
// baseline (3743.638 us; speedup 1.0000x reference)
//
#include <hip/hip_runtime.h>
#include <hip/hip_bf16.h>

#define N_NODES 100000
#define N_EDGES 3200000
#define DIM 64
#define OUT_COLS 256
#define BUCKET_SHIFT 6                                   // 64 nodes per bucket
#define NBUCK ((N_NODES + 63) / 64)                      // 1563
#define TILE 4096                                        // edges per binning block
#define NTILEBLK ((N_EDGES + TILE - 1) / TILE)           // 782
#define WFRAG_PER_LAYER (2 * 2 * 4 * 64 * 8)             // 8192 bf16 per layer

typedef __attribute__((ext_vector_type(8))) short short8;
typedef __attribute__((ext_vector_type(4))) float f32x4;

__device__ __forceinline__ unsigned short f2bf(float f) {
    __hip_bfloat16 b = __float2bfloat16(f);
    unsigned short u;
    __builtin_memcpy(&u, &b, 2);
    return u;
}
__device__ __forceinline__ unsigned int pkbf(float a, float b) {
    return (unsigned int)f2bf(a) | ((unsigned int)f2bf(b) << 16);
}
__device__ __forceinline__ float bflo(unsigned int p) { return __uint_as_float(p << 16); }
__device__ __forceinline__ float bfhi(unsigned int p) { return __uint_as_float(p & 0xFFFF0000u); }

// ---------------------------------------------------------------------------
// init: h = x ; hbf0 = bf16(x) ; out[:, 0:64] = x
// ---------------------------------------------------------------------------
__global__ void init_kernel(const float* __restrict__ x,
                            float* __restrict__ h,
                            unsigned short* __restrict__ h_bf,
                            float* __restrict__ out) {
    int i = blockIdx.x * blockDim.x + threadIdx.x;   // float4 index
    const int total = N_NODES * DIM / 4;
    if (i < total) {
        float4 v = ((const float4*)x)[i];
        ((float4*)h)[i] = v;
        int elem = i * 4;
        int node = elem >> 6;
        int c    = elem & 63;
        *(float4*)&out[node * OUT_COLS + c] = v;
        unsigned int lo = pkbf(v.x, v.y);
        unsigned int hi = pkbf(v.z, v.w);
        *(uint2*)&h_bf[elem] = make_uint2(lo, hi);
    }
}

// ---------------------------------------------------------------------------
// wprep: pack all 3 layers' W1/W2 into bf16 MFMA B-fragments.
// ---------------------------------------------------------------------------
__global__ __launch_bounds__(256) void wprep_kernel(const float* __restrict__ W1s,
                                                    const float* __restrict__ W2s,
                                                    unsigned short* __restrict__ wfrag) {
    int idx = blockIdx.x * 256 + threadIdx.x;
    if (idx >= 3 * WFRAG_PER_LAYER) return;
    int j     = idx & 7;
    int lane  = (idx >> 3) & 63;
    int ct    = (idx >> 9) & 3;
    int kt    = (idx >> 11) & 1;
    int mat   = (idx >> 12) & 1;
    int layer = idx >> 13;
    int k   = kt * 32 + (lane >> 4) * 8 + j;
    int col = ct * 16 + (lane & 15);
    const float* W = (mat ? W2s : W1s) + (size_t)layer * DIM * DIM;
    wfrag[idx] = f2bf(W[k * DIM + col]);
}

// ---------------------------------------------------------------------------
// count: per-block LDS histogram of dst buckets -> mat[blk][b]. No global
// atomics.
// ---------------------------------------------------------------------------
__global__ __launch_bounds__(256) void count_kernel(const int* __restrict__ dst,
                                                    int* __restrict__ mat) {
    __shared__ int lc[NBUCK];
    for (int b = threadIdx.x; b < NBUCK; b += 256) lc[b] = 0;
    __syncthreads();
    const int base = blockIdx.x * TILE;
#pragma unroll
    for (int k = 0; k < TILE / 256; ++k) {
        int e = base + k * 256 + threadIdx.x;
        if (e < N_EDGES) atomicAdd(&lc[((unsigned)dst[e]) >> BUCKET_SHIFT], 1);
    }
    __syncthreads();
    int* row = mat + (size_t)blockIdx.x * NBUCK;
    for (int b = threadIdx.x; b < NBUCK; b += 256) row[b] = lc[b];
}

// ---------------------------------------------------------------------------
// scan2: per-bucket column-exclusive scan of mat over the 782 blocks
// (in-place), emitting bucket totals. One block per bucket.
// ---------------------------------------------------------------------------
__global__ __launch_bounds__(256) void scan2_kernel(int* __restrict__ mat,
                                                    int* __restrict__ bucket_count) {
    const int b = blockIdx.x;
    const int t = threadIdx.x;
    int cpre[4];
    int s = 0;
#pragma unroll
    for (int j = 0; j < 4; ++j) {
        int blk = t * 4 + j;
        cpre[j] = s;
        int v = (blk < NTILEBLK) ? mat[(size_t)blk * NBUCK + b] : 0;
        s += v;
    }
    __shared__ int ss[256];
    ss[t] = s;
    __syncthreads();
    for (int off = 1; off < 256; off <<= 1) {
        int u = (t >= off) ? ss[t - off] : 0;
        __syncthreads();
        ss[t] += u;
        __syncthreads();
    }
    int excl = ss[t] - s;
#pragma unroll
    for (int j = 0; j < 4; ++j) {
        int blk = t * 4 + j;
        if (blk < NTILEBLK) mat[(size_t)blk * NBUCK + b] = excl + cpre[j];
    }
    if (t == 255) bucket_count[b] = ss[255];
}

// ---------------------------------------------------------------------------
// bucket_scan: exclusive scan of 1563 bucket counts -> bucket_base
// (1024 threads, 2 elements each)
// ---------------------------------------------------------------------------
__global__ __launch_bounds__(1024) void bucket_scan_kernel(const int* __restrict__ bucket_count,
                                                           int* __restrict__ bucket_base) {
    __shared__ int s[2048];
    const int t = threadIdx.x;
    int v0 = (t < NBUCK) ? bucket_count[t] : 0;
    int v1 = (t + 1024 < NBUCK) ? bucket_count[t + 1024] : 0;
    s[t] = v0; s[t + 1024] = v1;
    __syncthreads();
    for (int off = 1; off < 2048; off <<= 1) {
        int u0 = (t >= off) ? s[t - off] : 0;
        int u1 = ((t + 1024) >= off) ? s[t + 1024 - off] : 0;
        __syncthreads();
        s[t] += u0;
        s[t + 1024] += u1;
        __syncthreads();
    }
    if (t < NBUCK) bucket_base[t] = s[t] - v0;
    if (t + 1024 < NBUCK) bucket_base[t + 1024] = s[t + 1024] - v1;
}

// ---------------------------------------------------------------------------
// binA: LDS counting-sort per block (1563 buckets now), coalesced
// run-contiguous writeout. Zero global atomics: run bases precomputed via
// mat column prefix. Record = {src | dstlocal6<<24, a}.
// ---------------------------------------------------------------------------
__global__ __launch_bounds__(256) void binA_kernel(const int* __restrict__ src,
                                                   const int* __restrict__ dst,
                                                   const float* __restrict__ a,
                                                   const int* __restrict__ bucket_base,
                                                   const int* __restrict__ mat,
                                                   int2* __restrict__ temp) {
    __shared__ int lcount[2048];           // counts; reused as lgbase later
    __shared__ int lexcl[2048];            // block-local exclusive prefix
    __shared__ int ssum[256];
    __shared__ int2 stage[TILE];           // 32 KB
    __shared__ unsigned short sbuck[TILE]; // 8 KB

    const int t = threadIdx.x;
    const int base = blockIdx.x * TILE;

    for (int i = t; i < 2048; i += 256) lcount[i] = 0;
    __syncthreads();

    // phase 1: count + rank (LDS atomics only)
    int dv[TILE / 256], rk[TILE / 256];
#pragma unroll
    for (int k = 0; k < TILE / 256; ++k) {
        int e = base + k * 256 + t;
        dv[k] = 0; rk[k] = 0;
        if (e < N_EDGES) {
            int d = dst[e];
            dv[k] = d;
            rk[k] = atomicAdd(&lcount[((unsigned)d) >> BUCKET_SHIFT], 1);
        }
    }
    __syncthreads();

    // phase 2a: hierarchical exclusive scan (8 elems/thread over 2048)
    int pre[8];
    int s = 0;
#pragma unroll
    for (int j = 0; j < 8; ++j) {
        pre[j] = s;
        s += lcount[t * 8 + j];
    }
    ssum[t] = s;
    __syncthreads();
    for (int off = 1; off < 256; off <<= 1) {
        int u = (t >= off) ? ssum[t - off] : 0;
        __syncthreads();
        ssum[t] += u;
        __syncthreads();
    }
    int ex = ssum[t] - s;
#pragma unroll
    for (int j = 0; j < 8; ++j) lexcl[t * 8 + j] = ex + pre[j];
    __syncthreads();

    // phase 2b: run bases from precomputed column prefix (overwrite lcount)
    {
        const int* row = mat + (size_t)blockIdx.x * NBUCK;
        for (int b = t; b < NBUCK; b += 256) {
            lcount[b] = bucket_base[b] + row[b] - lexcl[b];
        }
    }
    __syncthreads();

    // phase 3: scatter into LDS, sorted by bucket
#pragma unroll
    for (int k = 0; k < TILE / 256; ++k) {
        int e = base + k * 256 + t;
        if (e < N_EDGES) {
            int d = dv[k];
            int b = ((unsigned)d) >> BUCKET_SHIFT;
            int slot = lexcl[b] + rk[k];
            stage[slot] = make_int2(src[e] | ((d & 63) << 24), __float_as_int(a[e]));
            sbuck[slot] = (unsigned short)b;
        }
    }
    __syncthreads();

    // phase 4: run-contiguous writeout
    const int cntT = min(TILE, N_EDGES - base);
    for (int i = t; i < cntT; i += 256) {
        temp[lcount[sbuck[i]] + i] = stage[i];
    }
}

// ---------------------------------------------------------------------------
// gup: fused gather + update. One block per 64-node bucket.
//   phase G: hn tile accumulated in LDS via ds_add_f32 (edges bucket-sorted
//            in temp; no per-node CSR needed)
//   phase T: t1 = h + hn ; t2 = h * hn  (bf16, swizzled LDS tiles)
//   phase M: mfma_f32_16x16x32_bf16 x16, epilogue leaky+add -> h, hbf_out, out
// h_bf is double-buffered across layers (gather reads foreign nodes).
// ---------------------------------------------------------------------------
__global__ __launch_bounds__(256) void gup_kernel(
        const unsigned short* __restrict__ hbf_in,
        const int2* __restrict__ temp,
        const int* __restrict__ bucket_base,
        const int* __restrict__ bucket_count,
        float* __restrict__ h,
        unsigned short* __restrict__ hbf_out,
        const unsigned short* __restrict__ wfrag,
        const float* __restrict__ b1,
        const float* __restrict__ b2,
        float* __restrict__ out,
        int out_col_base) {
    __shared__ float hnl[64][66];             // 16.9 KB (pad 66: 2-way banks max)
    __shared__ unsigned short t1s[64 * 64];   // 8 KB swizzled
    __shared__ unsigned short t2s[64 * 64];   // 8 KB

    const int t    = threadIdx.x;
    const int lane = t & 63;
    const int wid  = t >> 6;
    const int bkt  = blockIdx.x;
    const int node0 = bkt << 6;

    // zero hn tile
    for (int i = t; i < 64 * 66; i += 256) ((float*)hnl)[i] = 0.f;
    __syncthreads();

    // ---- phase G: gather into LDS ----
    {
        const int beg = bucket_base[bkt];
        const int cnt = bucket_count[bkt];
        const int hw  = t >> 5;            // 0..7 half-waves
        const int sub = t & 31;
        const int c2  = sub * 2;
        const int len = (cnt + 7) >> 3;
        const int i0 = hw * len;
        const int i1 = min(cnt, i0 + len);
        int i = i0;
        for (; i + 4 <= i1; i += 4) {
            int2 e0 = temp[beg + i + 0];
            int2 e1 = temp[beg + i + 1];
            int2 e2 = temp[beg + i + 2];
            int2 e3 = temp[beg + i + 3];
            unsigned p0 = *(const unsigned*)&hbf_in[(size_t)(e0.x & 0xFFFFFF) * DIM + c2];
            unsigned p1 = *(const unsigned*)&hbf_in[(size_t)(e1.x & 0xFFFFFF) * DIM + c2];
            unsigned p2 = *(const unsigned*)&hbf_in[(size_t)(e2.x & 0xFFFFFF) * DIM + c2];
            unsigned p3 = *(const unsigned*)&hbf_in[(size_t)(e3.x & 0xFFFFFF) * DIM + c2];
            float w0 = __int_as_float(e0.y);
            float w1 = __int_as_float(e1.y);
            float w2 = __int_as_float(e2.y);
            float w3 = __int_as_float(e3.y);
            int l0 = ((unsigned)e0.x) >> 24;
            int l1 = ((unsigned)e1.x) >> 24;
            int l2 = ((unsigned)e2.x) >> 24;
            int l3 = ((unsigned)e3.x) >> 24;
            atomicAdd(&hnl[l0][c2], w0 * bflo(p0));  atomicAdd(&hnl[l0][c2 + 1], w0 * bfhi(p0));
            atomicAdd(&hnl[l1][c2], w1 * bflo(p1));  atomicAdd(&hnl[l1][c2 + 1], w1 * bfhi(p1));
            atomicAdd(&hnl[l2][c2], w2 * bflo(p2));  atomicAdd(&hnl[l2][c2 + 1], w2 * bfhi(p2));
            atomicAdd(&hnl[l3][c2], w3 * bflo(p3));  atomicAdd(&hnl[l3][c2 + 1], w3 * bfhi(p3));
        }
        for (; i < i1; ++i) {
            int2 e = temp[beg + i];
            unsigned p = *(const unsigned*)&hbf_in[(size_t)(e.x & 0xFFFFFF) * DIM + c2];
            float w = __int_as_float(e.y);
            int l0 = ((unsigned)e.x) >> 24;
            atomicAdd(&hnl[l0][c2], w * bflo(p));
            atomicAdd(&hnl[l0][c2 + 1], w * bfhi(p));
        }
    }

    // ---- load W fragments + biases (independent of gather; L2-hot) ----
    short8 w1f[2][4], w2f[2][4];
#pragma unroll
    for (int kt = 0; kt < 2; ++kt)
#pragma unroll
        for (int ct = 0; ct < 4; ++ct) {
            w1f[kt][ct] = *(const short8*)(wfrag + (((0 * 2 + kt) * 4 + ct) * 64 + lane) * 8);
            w2f[kt][ct] = *(const short8*)(wfrag + (((1 * 2 + kt) * 4 + ct) * 64 + lane) * 8);
        }
    float bb1[4], bb2[4];
#pragma unroll
    for (int ct = 0; ct < 4; ++ct) {
        bb1[ct] = b1[ct * 16 + (lane & 15)];
        bb2[ct] = b2[ct * 16 + (lane & 15)];
    }
    __syncthreads();

    // ---- phase T: build bf16 t1/t2 tiles (h from global, hn from LDS) ----
    {
        const int row = t >> 2;
        const int kc  = (t & 3) * 16;
        const int node = node0 + row;
        float tv1[16], tv2[16];
        if (node < N_NODES) {
            const float4* hp = (const float4*)&h[(size_t)node * DIM + kc];
#pragma unroll
            for (int i4 = 0; i4 < 4; ++i4) {
                float4 av = hp[i4];
                float n0 = hnl[row][kc + i4 * 4 + 0];
                float n1 = hnl[row][kc + i4 * 4 + 1];
                float n2 = hnl[row][kc + i4 * 4 + 2];
                float n3 = hnl[row][kc + i4 * 4 + 3];
                tv1[i4 * 4 + 0] = av.x + n0;  tv2[i4 * 4 + 0] = av.x * n0;
                tv1[i4 * 4 + 1] = av.y + n1;  tv2[i4 * 4 + 1] = av.y * n1;
                tv1[i4 * 4 + 2] = av.z + n2;  tv2[i4 * 4 + 2] = av.z * n2;
                tv1[i4 * 4 + 3] = av.w + n3;  tv2[i4 * 4 + 3] = av.w * n3;
            }
        } else {
#pragma unroll
            for (int i = 0; i < 16; ++i) { tv1[i] = 0.f; tv2[i] = 0.f; }
        }
        const int sw = (row & 7) << 4;
        const int sbase = row * 128 + (t & 3) * 32;
        uint4 q;
        q.x = pkbf(tv1[0], tv1[1]);   q.y = pkbf(tv1[2], tv1[3]);
        q.z = pkbf(tv1[4], tv1[5]);   q.w = pkbf(tv1[6], tv1[7]);
        *(uint4*)((char*)t1s + ((sbase) ^ sw)) = q;
        q.x = pkbf(tv1[8], tv1[9]);   q.y = pkbf(tv1[10], tv1[11]);
        q.z = pkbf(tv1[12], tv1[13]); q.w = pkbf(tv1[14], tv1[15]);
        *(uint4*)((char*)t1s + ((sbase + 16) ^ sw)) = q;
        q.x = pkbf(tv2[0], tv2[1]);   q.y = pkbf(tv2[2], tv2[3]);
        q.z = pkbf(tv2[4], tv2[5]);   q.w = pkbf(tv2[6], tv2[7]);
        *(uint4*)((char*)t2s + ((sbase) ^ sw)) = q;
        q.x = pkbf(tv2[8], tv2[9]);   q.y = pkbf(tv2[10], tv2[11]);
        q.z = pkbf(tv2[12], tv2[13]); q.w = pkbf(tv2[14], tv2[15]);
        *(uint4*)((char*)t2s + ((sbase + 16) ^ sw)) = q;
    }
    __syncthreads();

    // ---- phase M: MFMA ----
    const int arow = wid * 16 + (lane & 15);
    const int asw  = (arow & 7) << 4;
    short8 a1[2], a2[2];
#pragma unroll
    for (int kt = 0; kt < 2; ++kt) {
        int ab = (arow * 128 + kt * 64 + ((lane >> 4) << 4)) ^ asw;
        a1[kt] = *(const short8*)((const char*)t1s + ab);
        a2[kt] = *(const short8*)((const char*)t2s + ab);
    }

    f32x4 acc1[4], acc2[4];
#pragma unroll
    for (int ct = 0; ct < 4; ++ct) {
        acc1[ct] = (f32x4){bb1[ct], bb1[ct], bb1[ct], bb1[ct]};
        acc2[ct] = (f32x4){bb2[ct], bb2[ct], bb2[ct], bb2[ct]};
    }
#pragma unroll
    for (int ct = 0; ct < 4; ++ct) {
        acc1[ct] = __builtin_amdgcn_mfma_f32_16x16x32_bf16(a1[0], w1f[0][ct], acc1[ct], 0, 0, 0);
        acc1[ct] = __builtin_amdgcn_mfma_f32_16x16x32_bf16(a1[1], w1f[1][ct], acc1[ct], 0, 0, 0);
        acc2[ct] = __builtin_amdgcn_mfma_f32_16x16x32_bf16(a2[0], w2f[0][ct], acc2[ct], 0, 0, 0);
        acc2[ct] = __builtin_amdgcn_mfma_f32_16x16x32_bf16(a2[1], w2f[1][ct], acc2[ct], 0, 0, 0);
    }

    // ---- epilogue: leaky + add, write h / hbf_out / out ----
#pragma unroll
    for (int ct = 0; ct < 4; ++ct) {
        const int col = ct * 16 + (lane & 15);
#pragma unroll
        for (int r = 0; r < 4; ++r) {
            const int grow = node0 + wid * 16 + (lane >> 4) * 4 + r;
            if (grow < N_NODES) {
                float v1 = acc1[ct][r]; v1 = v1 > 0.f ? v1 : 0.01f * v1;
                float v2 = acc2[ct][r]; v2 = v2 > 0.f ? v2 : 0.01f * v2;
                float hnew = v1 + v2;
                h[(size_t)grow * DIM + col] = hnew;
                hbf_out[(size_t)grow * DIM + col] = f2bf(hnew);
                out[(size_t)grow * OUT_COLS + out_col_base + col] = hnew;
            }
        }
    }
}

// ---------------------------------------------------------------------------
extern "C" void kernel_launch(void* const* d_in, const int* in_sizes, int n_in,
                              void* d_out, int out_size, void* d_ws, size_t ws_size,
                              hipStream_t stream) {
    const float* x   = (const float*)d_in[0];
    const float* a   = (const float*)d_in[1];
    const float* W1s = (const float*)d_in[2];
    const float* b1s = (const float*)d_in[3];
    const float* W2s = (const float*)d_in[4];
    const float* b2s = (const float*)d_in[5];
    const int*   src = (const int*)d_in[6];
    const int*   dst = (const int*)d_in[7];
    float* out = (float*)d_out;

    // workspace layout (no hn, no edges, no offsets anymore)
    float* h = (float*)d_ws;                                           // [N,64] fp32
    int2* temp = (int2*)(h + (size_t)N_NODES * DIM);                   // [E] bucket-sorted edges
    unsigned short* hbf0 = (unsigned short*)(temp + (size_t)N_EDGES);  // [N,64] bf16
    unsigned short* hbf1 = hbf0 + (size_t)N_NODES * DIM;               // [N,64] bf16
    int* bucket_count = (int*)(hbf1 + (size_t)N_NODES * DIM);          // [NBUCK]
    int* bucket_base  = bucket_count + NBUCK;                          // [NBUCK]
    uintptr_t p2 = (uintptr_t)(bucket_base + NBUCK);
    p2 = (p2 + 15) & ~(uintptr_t)15;
    unsigned short* wfrag = (unsigned short*)p2;                       // [3*8192] bf16 frags
    uintptr_t p3 = (uintptr_t)(wfrag + 3 * WFRAG_PER_LAYER);
    p3 = (p3 + 15) & ~(uintptr_t)15;
    int* mat = (int*)p3;                                               // [NTILEBLK * NBUCK]

    // h = x ; hbf0 = bf16(x) ; out[:, :64] = x
    {
        int total = N_NODES * DIM / 4;
        init_kernel<<<(total + 255) / 256, 256, 0, stream>>>(x, h, hbf0, out);
    }

    // pack weight fragments
    wprep_kernel<<<(3 * WFRAG_PER_LAYER + 255) / 256, 256, 0, stream>>>(W1s, W2s, wfrag);

    // CSR-lite build (bucket-sorted only) — zero global atomics
    count_kernel<<<NTILEBLK, 256, 0, stream>>>(dst, mat);
    scan2_kernel<<<NBUCK, 256, 0, stream>>>(mat, bucket_count);
    bucket_scan_kernel<<<1, 1024, 0, stream>>>(bucket_count, bucket_base);
    binA_kernel<<<NTILEBLK, 256, 0, stream>>>(src, dst, a, bucket_base, mat, temp);

    // 3 fused gather+update layers; h_bf double-buffered
    const unsigned short* hin = hbf0;
    unsigned short* hout = hbf1;
    for (int l = 0; l < 3; ++l) {
        gup_kernel<<<NBUCK, 256, 0, stream>>>(
            hin, temp, bucket_base, bucket_count,
            h, hout,
            wfrag + (size_t)l * WFRAG_PER_LAYER,
            b1s + (size_t)l * DIM,
            b2s + (size_t)l * DIM,
            out, (l + 1) * DIM);
        unsigned short* tmp = hout;
        hout = (unsigned short*)hin;
        hin = tmp;
    }
}

// Round 5
// 673.676 us; speedup vs baseline: 5.5570x; 5.5570x over previous
//
#include <hip/hip_runtime.h>
#include <hip/hip_bf16.h>

#define N_NODES 100000
#define N_EDGES 3200000
#define DIM 64
#define OUT_COLS 256
#define BUCKET_SHIFT 8                                   // 256 nodes per bucket
#define NBUCK ((N_NODES + 255) / 256)                    // 391
#define TILE 4096                                        // edges per binning block
#define NTILEBLK ((N_EDGES + TILE - 1) / TILE)           // 782
#define NODE_TILES ((N_NODES + 63) / 64)                 // 1563 (64 nodes / gup block)
#define WFRAG_PER_LAYER (2 * 2 * 4 * 64 * 8)             // 8192 bf16 per layer

typedef __attribute__((ext_vector_type(8))) short short8;
typedef __attribute__((ext_vector_type(4))) float f32x4;

__device__ __forceinline__ unsigned short f2bf(float f) {
    __hip_bfloat16 b = __float2bfloat16(f);
    unsigned short u;
    __builtin_memcpy(&u, &b, 2);
    return u;
}
__device__ __forceinline__ unsigned int pkbf(float a, float b) {
    return (unsigned int)f2bf(a) | ((unsigned int)f2bf(b) << 16);
}
__device__ __forceinline__ float bflo(unsigned int p) { return __uint_as_float(p << 16); }
__device__ __forceinline__ float bfhi(unsigned int p) { return __uint_as_float(p & 0xFFFF0000u); }

// ---------------------------------------------------------------------------
// init: h = x ; hbf0 = bf16(x) ; out[:, 0:64] = x
// ---------------------------------------------------------------------------
__global__ void init_kernel(const float* __restrict__ x,
                            float* __restrict__ h,
                            unsigned short* __restrict__ h_bf,
                            float* __restrict__ out) {
    int i = blockIdx.x * blockDim.x + threadIdx.x;   // float4 index
    const int total = N_NODES * DIM / 4;
    if (i < total) {
        float4 v = ((const float4*)x)[i];
        ((float4*)h)[i] = v;
        int elem = i * 4;
        int node = elem >> 6;
        int c    = elem & 63;
        *(float4*)&out[node * OUT_COLS + c] = v;
        unsigned int lo = pkbf(v.x, v.y);
        unsigned int hi = pkbf(v.z, v.w);
        *(uint2*)&h_bf[elem] = make_uint2(lo, hi);
    }
}

// ---------------------------------------------------------------------------
// wprep: pack all 3 layers' W1/W2 into bf16 MFMA B-fragments.
// ---------------------------------------------------------------------------
__global__ __launch_bounds__(256) void wprep_kernel(const float* __restrict__ W1s,
                                                    const float* __restrict__ W2s,
                                                    unsigned short* __restrict__ wfrag) {
    int idx = blockIdx.x * 256 + threadIdx.x;
    if (idx >= 3 * WFRAG_PER_LAYER) return;
    int j     = idx & 7;
    int lane  = (idx >> 3) & 63;
    int ct    = (idx >> 9) & 3;
    int kt    = (idx >> 11) & 1;
    int mat   = (idx >> 12) & 1;
    int layer = idx >> 13;
    int k   = kt * 32 + (lane >> 4) * 8 + j;
    int col = ct * 16 + (lane & 15);
    const float* W = (mat ? W2s : W1s) + (size_t)layer * DIM * DIM;
    wfrag[idx] = f2bf(W[k * DIM + col]);
}

// ---------------------------------------------------------------------------
// count: per-block LDS histogram of dst buckets -> mat[blk][b]. No global
// atomics.
// ---------------------------------------------------------------------------
__global__ __launch_bounds__(256) void count_kernel(const int* __restrict__ dst,
                                                    int* __restrict__ mat) {
    __shared__ int lc[NBUCK];
    for (int b = threadIdx.x; b < NBUCK; b += 256) lc[b] = 0;
    __syncthreads();
    const int base = blockIdx.x * TILE;
#pragma unroll
    for (int k = 0; k < TILE / 256; ++k) {
        int e = base + k * 256 + threadIdx.x;
        if (e < N_EDGES) atomicAdd(&lc[((unsigned)dst[e]) >> BUCKET_SHIFT], 1);
    }
    __syncthreads();
    int* row = mat + (size_t)blockIdx.x * NBUCK;
    for (int b = threadIdx.x; b < NBUCK; b += 256) row[b] = lc[b];
}

// ---------------------------------------------------------------------------
// scan2: per-bucket column-exclusive scan of mat over the 782 blocks
// (in-place), emitting bucket totals. One block per bucket.
// ---------------------------------------------------------------------------
__global__ __launch_bounds__(256) void scan2_kernel(int* __restrict__ mat,
                                                    int* __restrict__ bucket_count) {
    const int b = blockIdx.x;
    const int t = threadIdx.x;
    int cpre[4];
    int s = 0;
#pragma unroll
    for (int j = 0; j < 4; ++j) {
        int blk = t * 4 + j;
        cpre[j] = s;
        int v = (blk < NTILEBLK) ? mat[(size_t)blk * NBUCK + b] : 0;
        s += v;
    }
    __shared__ int ss[256];
    ss[t] = s;
    __syncthreads();
    for (int off = 1; off < 256; off <<= 1) {
        int u = (t >= off) ? ss[t - off] : 0;
        __syncthreads();
        ss[t] += u;
        __syncthreads();
    }
    int excl = ss[t] - s;
#pragma unroll
    for (int j = 0; j < 4; ++j) {
        int blk = t * 4 + j;
        if (blk < NTILEBLK) mat[(size_t)blk * NBUCK + b] = excl + cpre[j];
    }
    if (t == 255) bucket_count[b] = ss[255];
}

// ---------------------------------------------------------------------------
// bucket_scan: exclusive scan of 391 bucket counts -> bucket_base
// ---------------------------------------------------------------------------
__global__ __launch_bounds__(512) void bucket_scan_kernel(const int* __restrict__ bucket_count,
                                                          int* __restrict__ bucket_base,
                                                          int* __restrict__ offsets) {
    __shared__ int s[512];
    const int t = threadIdx.x;
    int v = (t < NBUCK) ? bucket_count[t] : 0;
    s[t] = v;
    __syncthreads();
    for (int off = 1; off < 512; off <<= 1) {
        int u = (t >= off) ? s[t - off] : 0;
        __syncthreads();
        s[t] += u;
        __syncthreads();
    }
    if (t < NBUCK) bucket_base[t] = s[t] - v;
    if (t == 0) offsets[N_NODES] = N_EDGES;
}

// ---------------------------------------------------------------------------
// binA: LDS counting-sort per block, coalesced run-contiguous writeout.
// Zero global atomics (run bases precomputed via mat column prefix).
// Record = {src | dstlocal8<<24, a}.
// ---------------------------------------------------------------------------
__global__ __launch_bounds__(256) void binA_kernel(const int* __restrict__ src,
                                                   const int* __restrict__ dst,
                                                   const float* __restrict__ a,
                                                   const int* __restrict__ bucket_base,
                                                   const int* __restrict__ mat,
                                                   int2* __restrict__ temp) {
    __shared__ int lcount[NBUCK];
    __shared__ int lscan[512];
    __shared__ int lgbase[NBUCK];
    __shared__ int2 stage[TILE];
    __shared__ unsigned short sbuck[TILE];

    const int t = threadIdx.x;
    const int base = blockIdx.x * TILE;

    for (int b = t; b < NBUCK; b += 256) lcount[b] = 0;
    __syncthreads();

    // phase 1: count + rank (LDS atomics only, int — native)
    int dv[TILE / 256], rk[TILE / 256];
#pragma unroll
    for (int k = 0; k < TILE / 256; ++k) {
        int e = base + k * 256 + t;
        dv[k] = 0; rk[k] = 0;
        if (e < N_EDGES) {
            int d = dst[e];
            dv[k] = d;
            rk[k] = atomicAdd(&lcount[((unsigned)d) >> BUCKET_SHIFT], 1);
        }
    }
    __syncthreads();

    // phase 2a: inclusive scan of counts
    lscan[t]       = (t < NBUCK) ? lcount[t] : 0;
    lscan[t + 256] = (t + 256 < NBUCK) ? lcount[t + 256] : 0;
    __syncthreads();
    for (int off = 1; off < 512; off <<= 1) {
        int u0 = (t >= off) ? lscan[t - off] : 0;
        int u1 = ((t + 256) >= off) ? lscan[t + 256 - off] : 0;
        __syncthreads();
        lscan[t] += u0;
        lscan[t + 256] += u1;
        __syncthreads();
    }
    // phase 2b: run bases from precomputed column prefix (no atomics)
    {
        const int* row = mat + (size_t)blockIdx.x * NBUCK;
        for (int b = t; b < NBUCK; b += 256) {
            int excl = lscan[b] - lcount[b];
            lgbase[b] = bucket_base[b] + row[b] - excl;
        }
    }
    __syncthreads();

    // phase 3: scatter into LDS, sorted by bucket
#pragma unroll
    for (int k = 0; k < TILE / 256; ++k) {
        int e = base + k * 256 + t;
        if (e < N_EDGES) {
            int d = dv[k];
            int b = ((unsigned)d) >> BUCKET_SHIFT;
            int slot = (lscan[b] - lcount[b]) + rk[k];
            stage[slot] = make_int2(src[e] | ((d & 255) << 24), __float_as_int(a[e]));
            sbuck[slot] = (unsigned short)b;
        }
    }
    __syncthreads();

    // phase 4: coalesced run-contiguous writeout
    const int cntT = min(TILE, N_EDGES - base);
    for (int i = t; i < cntT; i += 256) {
        temp[lgbase[sbuck[i]] + i] = stage[i];
    }
}

// ---------------------------------------------------------------------------
// binB: one block per bucket -> CSR offsets + node-sorted edge placement
// (L2-local 64 KB window)
// ---------------------------------------------------------------------------
__global__ __launch_bounds__(256) void binB_kernel(const int2* __restrict__ temp,
                                                   const int* __restrict__ bucket_base,
                                                   const int* __restrict__ bucket_count,
                                                   int* __restrict__ offsets,
                                                   int2* __restrict__ edges) {
    const int b = blockIdx.x;
    const int node0 = b << BUCKET_SHIFT;
    const int nodes = min(256, N_NODES - node0);
    const int beg = bucket_base[b];
    const int cnt = bucket_count[b];
    const int t = threadIdx.x;

    __shared__ int ncount[256];
    __shared__ int ssc[256];
    __shared__ int ncur[256];
    ncount[t] = 0;
    __syncthreads();
    for (int i = t; i < cnt; i += 256) {
        unsigned w0 = (unsigned)temp[beg + i].x;
        atomicAdd(&ncount[w0 >> 24], 1);
    }
    __syncthreads();
    int v = ncount[t];
    ssc[t] = v;
    __syncthreads();
    for (int off = 1; off < 256; off <<= 1) {
        int u = (t >= off) ? ssc[t - off] : 0;
        __syncthreads();
        ssc[t] += u;
        __syncthreads();
    }
    int excl = ssc[t] - v;
    if (t < nodes) offsets[node0 + t] = beg + excl;
    ncur[t] = beg + excl;
    __syncthreads();
    for (int i = t; i < cnt; i += 256) {
        int2 r = temp[beg + i];
        int loc = ((unsigned)r.x) >> 24;
        int pos = atomicAdd(&ncur[loc], 1);
        edges[pos] = make_int2(r.x & 0xFFFFFF, r.y);
    }
}

// ---------------------------------------------------------------------------
// gup: fused gather + update, ZERO atomics. One block per 64 nodes.
//   phase G+T: each half-wave gathers its 8 nodes in REGISTERS (edges are
//     node-sorted CSR — identical loop & math to the proven R3 gather),
//     then immediately builds the swizzled bf16 t1/t2 row in LDS (plain
//     ds_write_b32, 2 lanes/bank = conflict-free).
//   phase M: mfma_f32_16x16x32_bf16 x16 + leaky epilogue -> h, hbf_out, out.
// h_bf double-buffered across layers (gather reads foreign nodes).
// ---------------------------------------------------------------------------
__global__ __launch_bounds__(256) void gup_kernel(
        const unsigned short* __restrict__ hbf_in,
        const int2* __restrict__ edges,
        const int* __restrict__ offsets,
        float* __restrict__ h,
        unsigned short* __restrict__ hbf_out,
        const unsigned short* __restrict__ wfrag,
        const float* __restrict__ b1,
        const float* __restrict__ b2,
        float* __restrict__ out,
        int out_col_base) {
    __shared__ unsigned short t1s[64 * 64];   // 8 KB swizzled
    __shared__ unsigned short t2s[64 * 64];   // 8 KB

    const int t    = threadIdx.x;
    const int lane = t & 63;
    const int wid  = t >> 6;
    const int node0 = blockIdx.x * 64;
    const int hw   = t >> 5;            // half-wave id 0..7
    const int sub  = t & 31;
    const int c2   = sub * 2;

    // ---- phase G+T ----
#pragma unroll 1
    for (int j = 0; j < 8; ++j) {
        const int row  = hw * 8 + j;    // 0..63
        const int node = node0 + row;
        float t1lo = 0.f, t1hi = 0.f, t2lo = 0.f, t2hi = 0.f;
        if (node < N_NODES) {
            const int beg = offsets[node];
            const int end = offsets[node + 1];
            float al0 = 0.f, al1 = 0.f, al2 = 0.f, al3 = 0.f;
            float ah0 = 0.f, ah1 = 0.f, ah2 = 0.f, ah3 = 0.f;
            int i = beg;
            for (; i + 4 <= end; i += 4) {
                int2 e0 = edges[i + 0];
                int2 e1 = edges[i + 1];
                int2 e2 = edges[i + 2];
                int2 e3 = edges[i + 3];
                unsigned p0 = *(const unsigned*)&hbf_in[(size_t)e0.x * DIM + c2];
                unsigned p1 = *(const unsigned*)&hbf_in[(size_t)e1.x * DIM + c2];
                unsigned p2 = *(const unsigned*)&hbf_in[(size_t)e2.x * DIM + c2];
                unsigned p3 = *(const unsigned*)&hbf_in[(size_t)e3.x * DIM + c2];
                float w0 = __int_as_float(e0.y);
                float w1 = __int_as_float(e1.y);
                float w2 = __int_as_float(e2.y);
                float w3 = __int_as_float(e3.y);
                al0 = fmaf(w0, bflo(p0), al0);  ah0 = fmaf(w0, bfhi(p0), ah0);
                al1 = fmaf(w1, bflo(p1), al1);  ah1 = fmaf(w1, bfhi(p1), ah1);
                al2 = fmaf(w2, bflo(p2), al2);  ah2 = fmaf(w2, bfhi(p2), ah2);
                al3 = fmaf(w3, bflo(p3), al3);  ah3 = fmaf(w3, bfhi(p3), ah3);
            }
            for (; i < end; ++i) {
                int2 e = edges[i];
                unsigned p = *(const unsigned*)&hbf_in[(size_t)e.x * DIM + c2];
                float w = __int_as_float(e.y);
                al0 = fmaf(w, bflo(p), al0);
                ah0 = fmaf(w, bfhi(p), ah0);
            }
            float lo = (al0 + al1) + (al2 + al3);
            float hi = (ah0 + ah1) + (ah2 + ah3);
            float2 hv = *(const float2*)&h[(size_t)node * DIM + c2];
            t1lo = hv.x + lo;  t1hi = hv.y + hi;
            t2lo = hv.x * lo;  t2hi = hv.y * hi;
        }
        const int sw = (row & 7) << 4;
        const int bo = (row * 128 + sub * 4) ^ sw;
        *(unsigned*)((char*)t1s + bo) = pkbf(t1lo, t1hi);
        *(unsigned*)((char*)t2s + bo) = pkbf(t2lo, t2hi);
    }

    // ---- W fragments + biases (L2-hot) ----
    short8 w1f[2][4], w2f[2][4];
#pragma unroll
    for (int kt = 0; kt < 2; ++kt)
#pragma unroll
        for (int ct = 0; ct < 4; ++ct) {
            w1f[kt][ct] = *(const short8*)(wfrag + (((0 * 2 + kt) * 4 + ct) * 64 + lane) * 8);
            w2f[kt][ct] = *(const short8*)(wfrag + (((1 * 2 + kt) * 4 + ct) * 64 + lane) * 8);
        }
    float bb1[4], bb2[4];
#pragma unroll
    for (int ct = 0; ct < 4; ++ct) {
        bb1[ct] = b1[ct * 16 + (lane & 15)];
        bb2[ct] = b2[ct * 16 + (lane & 15)];
    }
    __syncthreads();

    // ---- phase M: MFMA ----
    const int arow = wid * 16 + (lane & 15);
    const int asw  = (arow & 7) << 4;
    short8 a1[2], a2[2];
#pragma unroll
    for (int kt = 0; kt < 2; ++kt) {
        int ab = (arow * 128 + kt * 64 + ((lane >> 4) << 4)) ^ asw;
        a1[kt] = *(const short8*)((const char*)t1s + ab);
        a2[kt] = *(const short8*)((const char*)t2s + ab);
    }

    f32x4 acc1[4], acc2[4];
#pragma unroll
    for (int ct = 0; ct < 4; ++ct) {
        acc1[ct] = (f32x4){bb1[ct], bb1[ct], bb1[ct], bb1[ct]};
        acc2[ct] = (f32x4){bb2[ct], bb2[ct], bb2[ct], bb2[ct]};
    }
#pragma unroll
    for (int ct = 0; ct < 4; ++ct) {
        acc1[ct] = __builtin_amdgcn_mfma_f32_16x16x32_bf16(a1[0], w1f[0][ct], acc1[ct], 0, 0, 0);
        acc1[ct] = __builtin_amdgcn_mfma_f32_16x16x32_bf16(a1[1], w1f[1][ct], acc1[ct], 0, 0, 0);
        acc2[ct] = __builtin_amdgcn_mfma_f32_16x16x32_bf16(a2[0], w2f[0][ct], acc2[ct], 0, 0, 0);
        acc2[ct] = __builtin_amdgcn_mfma_f32_16x16x32_bf16(a2[1], w2f[1][ct], acc2[ct], 0, 0, 0);
    }

    // ---- epilogue: leaky + add, write h / hbf_out / out ----
#pragma unroll
    for (int ct = 0; ct < 4; ++ct) {
        const int col = ct * 16 + (lane & 15);
#pragma unroll
        for (int r = 0; r < 4; ++r) {
            const int grow = node0 + wid * 16 + (lane >> 4) * 4 + r;
            if (grow < N_NODES) {
                float v1 = acc1[ct][r]; v1 = v1 > 0.f ? v1 : 0.01f * v1;
                float v2 = acc2[ct][r]; v2 = v2 > 0.f ? v2 : 0.01f * v2;
                float hnew = v1 + v2;
                h[(size_t)grow * DIM + col] = hnew;
                hbf_out[(size_t)grow * DIM + col] = f2bf(hnew);
                out[(size_t)grow * OUT_COLS + out_col_base + col] = hnew;
            }
        }
    }
}

// ---------------------------------------------------------------------------
extern "C" void kernel_launch(void* const* d_in, const int* in_sizes, int n_in,
                              void* d_out, int out_size, void* d_ws, size_t ws_size,
                              hipStream_t stream) {
    const float* x   = (const float*)d_in[0];
    const float* a   = (const float*)d_in[1];
    const float* W1s = (const float*)d_in[2];
    const float* b1s = (const float*)d_in[3];
    const float* W2s = (const float*)d_in[4];
    const float* b2s = (const float*)d_in[5];
    const int*   src = (const int*)d_in[6];
    const int*   dst = (const int*)d_in[7];
    float* out = (float*)d_out;

    // workspace layout
    float* h = (float*)d_ws;                                           // [N,64] fp32
    int2* edges = (int2*)(h + (size_t)N_NODES * DIM);                  // [E] node-sorted CSR
    int2* temp  = edges + (size_t)N_EDGES;                             // [E] binA staging
    unsigned short* hbf0 = (unsigned short*)(temp + (size_t)N_EDGES);  // [N,64] bf16
    unsigned short* hbf1 = hbf0 + (size_t)N_NODES * DIM;               // [N,64] bf16
    int* offsets = (int*)(hbf1 + (size_t)N_NODES * DIM);               // [N+1]
    int* bucket_count = offsets + N_NODES + 1;                         // [NBUCK]
    int* bucket_base  = bucket_count + NBUCK;                          // [NBUCK]
    uintptr_t p2 = (uintptr_t)(bucket_base + NBUCK);
    p2 = (p2 + 15) & ~(uintptr_t)15;
    unsigned short* wfrag = (unsigned short*)p2;                       // [3*8192] bf16 frags
    uintptr_t p3 = (uintptr_t)(wfrag + 3 * WFRAG_PER_LAYER);
    p3 = (p3 + 15) & ~(uintptr_t)15;
    int* mat = (int*)p3;                                               // [NTILEBLK * NBUCK]

    // h = x ; hbf0 = bf16(x) ; out[:, :64] = x
    {
        int total = N_NODES * DIM / 4;
        init_kernel<<<(total + 255) / 256, 256, 0, stream>>>(x, h, hbf0, out);
    }

    // pack weight fragments
    wprep_kernel<<<(3 * WFRAG_PER_LAYER + 255) / 256, 256, 0, stream>>>(W1s, W2s, wfrag);

    // CSR build — zero global atomics (R3-proven)
    count_kernel<<<NTILEBLK, 256, 0, stream>>>(dst, mat);
    scan2_kernel<<<NBUCK, 256, 0, stream>>>(mat, bucket_count);
    bucket_scan_kernel<<<1, 512, 0, stream>>>(bucket_count, bucket_base, offsets);
    binA_kernel<<<NTILEBLK, 256, 0, stream>>>(src, dst, a, bucket_base, mat, temp);
    binB_kernel<<<NBUCK, 256, 0, stream>>>(temp, bucket_base, bucket_count, offsets, edges);

    // 3 fused gather+update layers; h_bf double-buffered
    const unsigned short* hin = hbf0;
    unsigned short* hout = hbf1;
    for (int l = 0; l < 3; ++l) {
        gup_kernel<<<NODE_TILES, 256, 0, stream>>>(
            hin, edges, offsets,
            h, hout,
            wfrag + (size_t)l * WFRAG_PER_LAYER,
            b1s + (size_t)l * DIM,
            b2s + (size_t)l * DIM,
            out, (l + 1) * DIM);
        unsigned short* tmp = hout;
        hout = (unsigned short*)hin;
        hin = tmp;
    }
}

// Round 6
// 523.448 us; speedup vs baseline: 7.1519x; 1.2870x over previous
//
#include <hip/hip_runtime.h>
#include <hip/hip_bf16.h>

#define N_NODES 100000
#define N_EDGES 3200000
#define DIM 64
#define OUT_COLS 256
#define BUCKET_SHIFT 8                                   // 256 nodes per bucket
#define NBUCK ((N_NODES + 255) / 256)                    // 391
#define TILE 4096                                        // edges per binning block
#define NTILEBLK ((N_EDGES + TILE - 1) / TILE)           // 782
#define NODE_TILES ((N_NODES + 63) / 64)                 // 1563 (64 nodes / update block)
#define PAD_NODES (NODE_TILES * 64)                      // 100032 (t1g/t2g rows, OOB-safe)
#define WFRAG_PER_LAYER (2 * 2 * 4 * 64 * 8)             // 8192 bf16 per layer

typedef __attribute__((ext_vector_type(8))) short short8;
typedef __attribute__((ext_vector_type(4))) float f32x4;

__device__ __forceinline__ unsigned short f2bf(float f) {
    __hip_bfloat16 b = __float2bfloat16(f);
    unsigned short u;
    __builtin_memcpy(&u, &b, 2);
    return u;
}
__device__ __forceinline__ unsigned int pkbf(float a, float b) {
    return (unsigned int)f2bf(a) | ((unsigned int)f2bf(b) << 16);
}
__device__ __forceinline__ float bflo(unsigned int p) { return __uint_as_float(p << 16); }
__device__ __forceinline__ float bfhi(unsigned int p) { return __uint_as_float(p & 0xFFFF0000u); }

// ---------------------------------------------------------------------------
// init: h = x ; h_bf = bf16(x) ; out[:, 0:64] = x
// ---------------------------------------------------------------------------
__global__ void init_kernel(const float* __restrict__ x,
                            float* __restrict__ h,
                            unsigned short* __restrict__ h_bf,
                            float* __restrict__ out) {
    int i = blockIdx.x * blockDim.x + threadIdx.x;   // float4 index
    const int total = N_NODES * DIM / 4;
    if (i < total) {
        float4 v = ((const float4*)x)[i];
        ((float4*)h)[i] = v;
        int elem = i * 4;
        int node = elem >> 6;
        int c    = elem & 63;
        *(float4*)&out[node * OUT_COLS + c] = v;
        unsigned int lo = pkbf(v.x, v.y);
        unsigned int hi = pkbf(v.z, v.w);
        *(uint2*)&h_bf[elem] = make_uint2(lo, hi);
    }
}

// ---------------------------------------------------------------------------
// wprep: pack all 3 layers' W1/W2 into bf16 MFMA B-fragments.
// ---------------------------------------------------------------------------
__global__ __launch_bounds__(256) void wprep_kernel(const float* __restrict__ W1s,
                                                    const float* __restrict__ W2s,
                                                    unsigned short* __restrict__ wfrag) {
    int idx = blockIdx.x * 256 + threadIdx.x;
    if (idx >= 3 * WFRAG_PER_LAYER) return;
    int j     = idx & 7;
    int lane  = (idx >> 3) & 63;
    int ct    = (idx >> 9) & 3;
    int kt    = (idx >> 11) & 1;
    int mat   = (idx >> 12) & 1;
    int layer = idx >> 13;
    int k   = kt * 32 + (lane >> 4) * 8 + j;
    int col = ct * 16 + (lane & 15);
    const float* W = (mat ? W2s : W1s) + (size_t)layer * DIM * DIM;
    wfrag[idx] = f2bf(W[k * DIM + col]);
}

// ---------------------------------------------------------------------------
// count: per-block LDS histogram of dst buckets -> mat[blk][b]. No global
// atomics.
// ---------------------------------------------------------------------------
__global__ __launch_bounds__(256) void count_kernel(const int* __restrict__ dst,
                                                    int* __restrict__ mat) {
    __shared__ int lc[NBUCK];
    for (int b = threadIdx.x; b < NBUCK; b += 256) lc[b] = 0;
    __syncthreads();
    const int base = blockIdx.x * TILE;
#pragma unroll
    for (int k = 0; k < TILE / 256; ++k) {
        int e = base + k * 256 + threadIdx.x;
        if (e < N_EDGES) atomicAdd(&lc[((unsigned)dst[e]) >> BUCKET_SHIFT], 1);
    }
    __syncthreads();
    int* row = mat + (size_t)blockIdx.x * NBUCK;
    for (int b = threadIdx.x; b < NBUCK; b += 256) row[b] = lc[b];
}

// ---------------------------------------------------------------------------
// scan2: per-bucket column-exclusive scan of mat over the 782 blocks
// (in-place), emitting bucket totals. One block per bucket.
// ---------------------------------------------------------------------------
__global__ __launch_bounds__(256) void scan2_kernel(int* __restrict__ mat,
                                                    int* __restrict__ bucket_count) {
    const int b = blockIdx.x;
    const int t = threadIdx.x;
    int cpre[4];
    int s = 0;
#pragma unroll
    for (int j = 0; j < 4; ++j) {
        int blk = t * 4 + j;
        cpre[j] = s;
        int v = (blk < NTILEBLK) ? mat[(size_t)blk * NBUCK + b] : 0;
        s += v;
    }
    __shared__ int ss[256];
    ss[t] = s;
    __syncthreads();
    for (int off = 1; off < 256; off <<= 1) {
        int u = (t >= off) ? ss[t - off] : 0;
        __syncthreads();
        ss[t] += u;
        __syncthreads();
    }
    int excl = ss[t] - s;
#pragma unroll
    for (int j = 0; j < 4; ++j) {
        int blk = t * 4 + j;
        if (blk < NTILEBLK) mat[(size_t)blk * NBUCK + b] = excl + cpre[j];
    }
    if (t == 255) bucket_count[b] = ss[255];
}

// ---------------------------------------------------------------------------
// bucket_scan: exclusive scan of 391 bucket counts -> bucket_base
// ---------------------------------------------------------------------------
__global__ __launch_bounds__(512) void bucket_scan_kernel(const int* __restrict__ bucket_count,
                                                          int* __restrict__ bucket_base,
                                                          int* __restrict__ offsets) {
    __shared__ int s[512];
    const int t = threadIdx.x;
    int v = (t < NBUCK) ? bucket_count[t] : 0;
    s[t] = v;
    __syncthreads();
    for (int off = 1; off < 512; off <<= 1) {
        int u = (t >= off) ? s[t - off] : 0;
        __syncthreads();
        s[t] += u;
        __syncthreads();
    }
    if (t < NBUCK) bucket_base[t] = s[t] - v;
    if (t == 0) offsets[N_NODES] = N_EDGES;
}

// ---------------------------------------------------------------------------
// binA: LDS counting-sort per block, coalesced run-contiguous writeout.
// Zero global atomics (run bases precomputed via mat column prefix).
// Record = {src | dstlocal8<<24, a}.
// ---------------------------------------------------------------------------
__global__ __launch_bounds__(256) void binA_kernel(const int* __restrict__ src,
                                                   const int* __restrict__ dst,
                                                   const float* __restrict__ a,
                                                   const int* __restrict__ bucket_base,
                                                   const int* __restrict__ mat,
                                                   int2* __restrict__ temp) {
    __shared__ int lcount[NBUCK];
    __shared__ int lscan[512];
    __shared__ int lgbase[NBUCK];
    __shared__ int2 stage[TILE];
    __shared__ unsigned short sbuck[TILE];

    const int t = threadIdx.x;
    const int base = blockIdx.x * TILE;

    for (int b = t; b < NBUCK; b += 256) lcount[b] = 0;
    __syncthreads();

    // phase 1: count + rank (LDS atomics only, int — native)
    int dv[TILE / 256], rk[TILE / 256];
#pragma unroll
    for (int k = 0; k < TILE / 256; ++k) {
        int e = base + k * 256 + t;
        dv[k] = 0; rk[k] = 0;
        if (e < N_EDGES) {
            int d = dst[e];
            dv[k] = d;
            rk[k] = atomicAdd(&lcount[((unsigned)d) >> BUCKET_SHIFT], 1);
        }
    }
    __syncthreads();

    // phase 2a: inclusive scan of counts
    lscan[t]       = (t < NBUCK) ? lcount[t] : 0;
    lscan[t + 256] = (t + 256 < NBUCK) ? lcount[t + 256] : 0;
    __syncthreads();
    for (int off = 1; off < 512; off <<= 1) {
        int u0 = (t >= off) ? lscan[t - off] : 0;
        int u1 = ((t + 256) >= off) ? lscan[t + 256 - off] : 0;
        __syncthreads();
        lscan[t] += u0;
        lscan[t + 256] += u1;
        __syncthreads();
    }
    // phase 2b: run bases from precomputed column prefix (no atomics)
    {
        const int* row = mat + (size_t)blockIdx.x * NBUCK;
        for (int b = t; b < NBUCK; b += 256) {
            int excl = lscan[b] - lcount[b];
            lgbase[b] = bucket_base[b] + row[b] - excl;
        }
    }
    __syncthreads();

    // phase 3: scatter into LDS, sorted by bucket
#pragma unroll
    for (int k = 0; k < TILE / 256; ++k) {
        int e = base + k * 256 + t;
        if (e < N_EDGES) {
            int d = dv[k];
            int b = ((unsigned)d) >> BUCKET_SHIFT;
            int slot = (lscan[b] - lcount[b]) + rk[k];
            stage[slot] = make_int2(src[e] | ((d & 255) << 24), __float_as_int(a[e]));
            sbuck[slot] = (unsigned short)b;
        }
    }
    __syncthreads();

    // phase 4: coalesced run-contiguous writeout
    const int cntT = min(TILE, N_EDGES - base);
    for (int i = t; i < cntT; i += 256) {
        temp[lgbase[sbuck[i]] + i] = stage[i];
    }
}

// ---------------------------------------------------------------------------
// binB: one block per bucket -> CSR offsets + node-sorted edge placement
// (L2-local 64 KB window)
// ---------------------------------------------------------------------------
__global__ __launch_bounds__(256) void binB_kernel(const int2* __restrict__ temp,
                                                   const int* __restrict__ bucket_base,
                                                   const int* __restrict__ bucket_count,
                                                   int* __restrict__ offsets,
                                                   int2* __restrict__ edges) {
    const int b = blockIdx.x;
    const int node0 = b << BUCKET_SHIFT;
    const int nodes = min(256, N_NODES - node0);
    const int beg = bucket_base[b];
    const int cnt = bucket_count[b];
    const int t = threadIdx.x;

    __shared__ int ncount[256];
    __shared__ int ssc[256];
    __shared__ int ncur[256];
    ncount[t] = 0;
    __syncthreads();
    for (int i = t; i < cnt; i += 256) {
        unsigned w0 = (unsigned)temp[beg + i].x;
        atomicAdd(&ncount[w0 >> 24], 1);
    }
    __syncthreads();
    int v = ncount[t];
    ssc[t] = v;
    __syncthreads();
    for (int off = 1; off < 256; off <<= 1) {
        int u = (t >= off) ? ssc[t - off] : 0;
        __syncthreads();
        ssc[t] += u;
        __syncthreads();
    }
    int excl = ssc[t] - v;
    if (t < nodes) offsets[node0 + t] = beg + excl;
    ncur[t] = beg + excl;
    __syncthreads();
    for (int i = t; i < cnt; i += 256) {
        int2 r = temp[beg + i];
        int loc = ((unsigned)r.x) >> 24;
        int pos = atomicAdd(&ncur[loc], 1);
        edges[pos] = make_int2(r.x & 0xFFFFFF, r.y);
    }
}

// ---------------------------------------------------------------------------
// gather_t12: hn[v] = sum a_e * h_bf[u] (8-deep ILP), then immediately
// t1 = h + hn ; t2 = h * hn packed to bf16 row-major -> t1g/t2g.
// Half-wave (32 lanes) per node; lane covers 2 cols. No LDS -> max occupancy,
// 12500 independent blocks (latency-bound random reads need the parallelism).
// ---------------------------------------------------------------------------
__global__ __launch_bounds__(256) void gather_t12_kernel(
        const unsigned short* __restrict__ h_bf,
        const float* __restrict__ h,
        const int2* __restrict__ edges,
        const int* __restrict__ offsets,
        unsigned short* __restrict__ t1g,
        unsigned short* __restrict__ t2g) {
    const int lane   = threadIdx.x & 63;
    const int half   = lane >> 5;
    const int sub    = lane & 31;
    const int waveid = (blockIdx.x * blockDim.x + threadIdx.x) >> 6;
    const int node   = waveid * 2 + half;
    if (node >= N_NODES) return;

    const int beg = offsets[node];
    const int end = offsets[node + 1];
    const int c2 = sub * 2;

    float al0=0.f,al1=0.f,al2=0.f,al3=0.f,al4=0.f,al5=0.f,al6=0.f,al7=0.f;
    float ah0=0.f,ah1=0.f,ah2=0.f,ah3=0.f,ah4=0.f,ah5=0.f,ah6=0.f,ah7=0.f;
    int i = beg;
    for (; i + 8 <= end; i += 8) {
        int4 q0 = *(const int4*)&edges[i + 0];   // e0,e1
        int4 q1 = *(const int4*)&edges[i + 2];   // e2,e3
        int4 q2 = *(const int4*)&edges[i + 4];   // e4,e5
        int4 q3 = *(const int4*)&edges[i + 6];   // e6,e7
        unsigned p0 = *(const unsigned*)&h_bf[(size_t)q0.x * DIM + c2];
        unsigned p1 = *(const unsigned*)&h_bf[(size_t)q0.z * DIM + c2];
        unsigned p2 = *(const unsigned*)&h_bf[(size_t)q1.x * DIM + c2];
        unsigned p3 = *(const unsigned*)&h_bf[(size_t)q1.z * DIM + c2];
        unsigned p4 = *(const unsigned*)&h_bf[(size_t)q2.x * DIM + c2];
        unsigned p5 = *(const unsigned*)&h_bf[(size_t)q2.z * DIM + c2];
        unsigned p6 = *(const unsigned*)&h_bf[(size_t)q3.x * DIM + c2];
        unsigned p7 = *(const unsigned*)&h_bf[(size_t)q3.z * DIM + c2];
        float w0 = __int_as_float(q0.y), w1 = __int_as_float(q0.w);
        float w2 = __int_as_float(q1.y), w3 = __int_as_float(q1.w);
        float w4 = __int_as_float(q2.y), w5 = __int_as_float(q2.w);
        float w6 = __int_as_float(q3.y), w7 = __int_as_float(q3.w);
        al0 = fmaf(w0, bflo(p0), al0);  ah0 = fmaf(w0, bfhi(p0), ah0);
        al1 = fmaf(w1, bflo(p1), al1);  ah1 = fmaf(w1, bfhi(p1), ah1);
        al2 = fmaf(w2, bflo(p2), al2);  ah2 = fmaf(w2, bfhi(p2), ah2);
        al3 = fmaf(w3, bflo(p3), al3);  ah3 = fmaf(w3, bfhi(p3), ah3);
        al4 = fmaf(w4, bflo(p4), al4);  ah4 = fmaf(w4, bfhi(p4), ah4);
        al5 = fmaf(w5, bflo(p5), al5);  ah5 = fmaf(w5, bfhi(p5), ah5);
        al6 = fmaf(w6, bflo(p6), al6);  ah6 = fmaf(w6, bfhi(p6), ah6);
        al7 = fmaf(w7, bflo(p7), al7);  ah7 = fmaf(w7, bfhi(p7), ah7);
    }
    for (; i < end; ++i) {
        int2 e = edges[i];
        unsigned p = *(const unsigned*)&h_bf[(size_t)e.x * DIM + c2];
        float w = __int_as_float(e.y);
        al0 = fmaf(w, bflo(p), al0);
        ah0 = fmaf(w, bfhi(p), ah0);
    }
    float lo = ((al0 + al1) + (al2 + al3)) + ((al4 + al5) + (al6 + al7));
    float hi = ((ah0 + ah1) + (ah2 + ah3)) + ((ah4 + ah5) + (ah6 + ah7));

    float2 hv = *(const float2*)&h[(size_t)node * DIM + c2];
    float t1l = hv.x + lo, t1h = hv.y + hi;
    float t2l = hv.x * lo, t2h = hv.y * hi;
    *(unsigned*)&t1g[(size_t)node * DIM + c2] = pkbf(t1l, t1h);
    *(unsigned*)&t2g[(size_t)node * DIM + c2] = pkbf(t2l, t2h);
}

// ---------------------------------------------------------------------------
// update (MFMA, no LDS): A-fragments loaded DIRECTLY from t1g/t2g (row-major
// bf16 — same fragment bytes the R3 LDS path produced). 16 MFMAs + leaky
// epilogue -> h, h_bf, out.
// ---------------------------------------------------------------------------
__global__ __launch_bounds__(256) void update_kernel(
        const unsigned short* __restrict__ t1g,
        const unsigned short* __restrict__ t2g,
        float* __restrict__ h,
        unsigned short* __restrict__ h_bf,
        const unsigned short* __restrict__ wfrag,
        const float* __restrict__ b1,
        const float* __restrict__ b2,
        float* __restrict__ out,
        int out_col_base) {
    const int t    = threadIdx.x;
    const int lane = t & 63;
    const int wid  = t >> 6;
    const int node0 = blockIdx.x * 64;

    // W fragments + biases (L2-hot)
    short8 w1f[2][4], w2f[2][4];
#pragma unroll
    for (int kt = 0; kt < 2; ++kt)
#pragma unroll
        for (int ct = 0; ct < 4; ++ct) {
            w1f[kt][ct] = *(const short8*)(wfrag + (((0 * 2 + kt) * 4 + ct) * 64 + lane) * 8);
            w2f[kt][ct] = *(const short8*)(wfrag + (((1 * 2 + kt) * 4 + ct) * 64 + lane) * 8);
        }
    float bb1[4], bb2[4];
#pragma unroll
    for (int ct = 0; ct < 4; ++ct) {
        bb1[ct] = b1[ct * 16 + (lane & 15)];
        bb2[ct] = b2[ct * 16 + (lane & 15)];
    }

    // A-fragments direct from global (t1g/t2g padded to PAD_NODES rows)
    const int arow = node0 + wid * 16 + (lane & 15);
    const size_t abase = (size_t)arow * DIM + ((lane >> 4) << 3);
    short8 a1[2], a2[2];
    a1[0] = *(const short8*)&t1g[abase];
    a1[1] = *(const short8*)&t1g[abase + 32];
    a2[0] = *(const short8*)&t2g[abase];
    a2[1] = *(const short8*)&t2g[abase + 32];

    f32x4 acc1[4], acc2[4];
#pragma unroll
    for (int ct = 0; ct < 4; ++ct) {
        acc1[ct] = (f32x4){bb1[ct], bb1[ct], bb1[ct], bb1[ct]};
        acc2[ct] = (f32x4){bb2[ct], bb2[ct], bb2[ct], bb2[ct]};
    }
#pragma unroll
    for (int ct = 0; ct < 4; ++ct) {
        acc1[ct] = __builtin_amdgcn_mfma_f32_16x16x32_bf16(a1[0], w1f[0][ct], acc1[ct], 0, 0, 0);
        acc1[ct] = __builtin_amdgcn_mfma_f32_16x16x32_bf16(a1[1], w1f[1][ct], acc1[ct], 0, 0, 0);
        acc2[ct] = __builtin_amdgcn_mfma_f32_16x16x32_bf16(a2[0], w2f[0][ct], acc2[ct], 0, 0, 0);
        acc2[ct] = __builtin_amdgcn_mfma_f32_16x16x32_bf16(a2[1], w2f[1][ct], acc2[ct], 0, 0, 0);
    }

    // epilogue: leaky + add, write h / h_bf / out
#pragma unroll
    for (int ct = 0; ct < 4; ++ct) {
        const int col = ct * 16 + (lane & 15);
#pragma unroll
        for (int r = 0; r < 4; ++r) {
            const int grow = node0 + wid * 16 + (lane >> 4) * 4 + r;
            if (grow < N_NODES) {
                float v1 = acc1[ct][r]; v1 = v1 > 0.f ? v1 : 0.01f * v1;
                float v2 = acc2[ct][r]; v2 = v2 > 0.f ? v2 : 0.01f * v2;
                float hnew = v1 + v2;
                h[(size_t)grow * DIM + col] = hnew;
                h_bf[(size_t)grow * DIM + col] = f2bf(hnew);
                out[(size_t)grow * OUT_COLS + out_col_base + col] = hnew;
            }
        }
    }
}

// ---------------------------------------------------------------------------
extern "C" void kernel_launch(void* const* d_in, const int* in_sizes, int n_in,
                              void* d_out, int out_size, void* d_ws, size_t ws_size,
                              hipStream_t stream) {
    const float* x   = (const float*)d_in[0];
    const float* a   = (const float*)d_in[1];
    const float* W1s = (const float*)d_in[2];
    const float* b1s = (const float*)d_in[3];
    const float* W2s = (const float*)d_in[4];
    const float* b2s = (const float*)d_in[5];
    const int*   src = (const int*)d_in[6];
    const int*   dst = (const int*)d_in[7];
    float* out = (float*)d_out;

    // workspace layout
    float* h = (float*)d_ws;                                           // [N,64] fp32
    int2* edges = (int2*)(h + (size_t)N_NODES * DIM);                  // [E] node-sorted CSR
    int2* temp  = edges + (size_t)N_EDGES;                             // [E] binA staging
    unsigned short* h_bf = (unsigned short*)(temp + (size_t)N_EDGES);  // [N,64] bf16
    unsigned short* t1g  = h_bf + (size_t)N_NODES * DIM;               // [PAD_NODES,64] bf16
    unsigned short* t2g  = t1g + (size_t)PAD_NODES * DIM;              // [PAD_NODES,64] bf16
    int* offsets = (int*)(t2g + (size_t)PAD_NODES * DIM);              // [N+1]
    int* bucket_count = offsets + N_NODES + 1;                         // [NBUCK]
    int* bucket_base  = bucket_count + NBUCK;                          // [NBUCK]
    uintptr_t p2 = (uintptr_t)(bucket_base + NBUCK);
    p2 = (p2 + 15) & ~(uintptr_t)15;
    unsigned short* wfrag = (unsigned short*)p2;                       // [3*8192] bf16 frags
    uintptr_t p3 = (uintptr_t)(wfrag + 3 * WFRAG_PER_LAYER);
    p3 = (p3 + 15) & ~(uintptr_t)15;
    int* mat = (int*)p3;                                               // [NTILEBLK * NBUCK]

    // h = x ; h_bf = bf16(x) ; out[:, :64] = x
    {
        int total = N_NODES * DIM / 4;
        init_kernel<<<(total + 255) / 256, 256, 0, stream>>>(x, h, h_bf, out);
    }

    // pack weight fragments
    wprep_kernel<<<(3 * WFRAG_PER_LAYER + 255) / 256, 256, 0, stream>>>(W1s, W2s, wfrag);

    // CSR build — zero global atomics (R3-proven)
    count_kernel<<<NTILEBLK, 256, 0, stream>>>(dst, mat);
    scan2_kernel<<<NBUCK, 256, 0, stream>>>(mat, bucket_count);
    bucket_scan_kernel<<<1, 512, 0, stream>>>(bucket_count, bucket_base, offsets);
    binA_kernel<<<NTILEBLK, 256, 0, stream>>>(src, dst, a, bucket_base, mat, temp);
    binB_kernel<<<NBUCK, 256, 0, stream>>>(temp, bucket_base, bucket_count, offsets, edges);

    // 3 layers: split gather (max parallelism) + short MFMA update
    for (int l = 0; l < 3; ++l) {
        int waves = (N_NODES + 1) / 2;
        int blocks = (waves * 64 + 255) / 256;
        gather_t12_kernel<<<blocks, 256, 0, stream>>>(h_bf, h, edges, offsets, t1g, t2g);
        update_kernel<<<NODE_TILES, 256, 0, stream>>>(
            t1g, t2g,
            h, h_bf,
            wfrag + (size_t)l * WFRAG_PER_LAYER,
            b1s + (size_t)l * DIM,
            b2s + (size_t)l * DIM,
            out, (l + 1) * DIM);
    }
}

// Round 7
// 480.916 us; speedup vs baseline: 7.7844x; 1.0884x over previous
//
#include <hip/hip_runtime.h>
#include <hip/hip_bf16.h>

#define N_NODES 100000
#define N_EDGES 3200000
#define DIM 64
#define OUT_COLS 256
#define BUCKET_SHIFT 8                                   // 256 nodes per bucket
#define NBUCK ((N_NODES + 255) / 256)                    // 391
#define TILE 4096                                        // edges per binning block
#define NTILEBLK ((N_EDGES + TILE - 1) / TILE)           // 782
#define NODE_TILES ((N_NODES + 63) / 64)                 // 1563 (64 nodes / update block)
#define PAD_NODES (NODE_TILES * 64)                      // 100032 (bf16 arrays padded)
#define WFRAG_PER_LAYER (2 * 2 * 4 * 64 * 8)             // 8192 bf16 per layer

typedef __attribute__((ext_vector_type(8))) short short8;
typedef __attribute__((ext_vector_type(4))) float f32x4;

__device__ __forceinline__ unsigned short f2bf(float f) {
    __hip_bfloat16 b = __float2bfloat16(f);
    unsigned short u;
    __builtin_memcpy(&u, &b, 2);
    return u;
}
__device__ __forceinline__ unsigned int pkbf(float a, float b) {
    return (unsigned int)f2bf(a) | ((unsigned int)f2bf(b) << 16);
}
__device__ __forceinline__ float bflo(unsigned int p) { return __uint_as_float(p << 16); }
__device__ __forceinline__ float bfhi(unsigned int p) { return __uint_as_float(p & 0xFFFF0000u); }
__device__ __forceinline__ float bfu(unsigned short u) { return __uint_as_float((unsigned)u << 16); }

// ---------------------------------------------------------------------------
// init: h_bf = bf16(x) ; out[:, 0:64] = x ; zero the pad rows of h_bf/hn_bf
// ---------------------------------------------------------------------------
__global__ void init_kernel(const float* __restrict__ x,
                            unsigned short* __restrict__ h_bf,
                            unsigned short* __restrict__ hn_bf,
                            float* __restrict__ out) {
    int i = blockIdx.x * blockDim.x + threadIdx.x;   // float4 / uint2 index
    const int total  = N_NODES * DIM / 4;
    const int ptotal = PAD_NODES * DIM / 4;
    if (i < total) {
        float4 v = ((const float4*)x)[i];
        int elem = i * 4;
        int node = elem >> 6;
        int c    = elem & 63;
        *(float4*)&out[node * OUT_COLS + c] = v;
        *(uint2*)&h_bf[elem] = make_uint2(pkbf(v.x, v.y), pkbf(v.z, v.w));
    } else if (i < ptotal) {
        int elem = i * 4;
        *(uint2*)&h_bf[elem]  = make_uint2(0u, 0u);
        *(uint2*)&hn_bf[elem] = make_uint2(0u, 0u);
    }
}

// ---------------------------------------------------------------------------
// wprep: pack all 3 layers' W1/W2 into bf16 MFMA B-fragments.
// ---------------------------------------------------------------------------
__global__ __launch_bounds__(256) void wprep_kernel(const float* __restrict__ W1s,
                                                    const float* __restrict__ W2s,
                                                    unsigned short* __restrict__ wfrag) {
    int idx = blockIdx.x * 256 + threadIdx.x;
    if (idx >= 3 * WFRAG_PER_LAYER) return;
    int j     = idx & 7;
    int lane  = (idx >> 3) & 63;
    int ct    = (idx >> 9) & 3;
    int kt    = (idx >> 11) & 1;
    int mat   = (idx >> 12) & 1;
    int layer = idx >> 13;
    int k   = kt * 32 + (lane >> 4) * 8 + j;
    int col = ct * 16 + (lane & 15);
    const float* W = (mat ? W2s : W1s) + (size_t)layer * DIM * DIM;
    wfrag[idx] = f2bf(W[k * DIM + col]);
}

// ---------------------------------------------------------------------------
// count: per-block LDS histogram of dst buckets -> mat[blk][b]. No global
// atomics.
// ---------------------------------------------------------------------------
__global__ __launch_bounds__(256) void count_kernel(const int* __restrict__ dst,
                                                    int* __restrict__ mat) {
    __shared__ int lc[NBUCK];
    for (int b = threadIdx.x; b < NBUCK; b += 256) lc[b] = 0;
    __syncthreads();
    const int base = blockIdx.x * TILE;
#pragma unroll
    for (int k = 0; k < TILE / 256; ++k) {
        int e = base + k * 256 + threadIdx.x;
        if (e < N_EDGES) atomicAdd(&lc[((unsigned)dst[e]) >> BUCKET_SHIFT], 1);
    }
    __syncthreads();
    int* row = mat + (size_t)blockIdx.x * NBUCK;
    for (int b = threadIdx.x; b < NBUCK; b += 256) row[b] = lc[b];
}

// ---------------------------------------------------------------------------
// scan2: per-bucket column-exclusive scan of mat over the 782 blocks
// (in-place), emitting bucket totals. One block per bucket.
// ---------------------------------------------------------------------------
__global__ __launch_bounds__(256) void scan2_kernel(int* __restrict__ mat,
                                                    int* __restrict__ bucket_count) {
    const int b = blockIdx.x;
    const int t = threadIdx.x;
    int cpre[4];
    int s = 0;
#pragma unroll
    for (int j = 0; j < 4; ++j) {
        int blk = t * 4 + j;
        cpre[j] = s;
        int v = (blk < NTILEBLK) ? mat[(size_t)blk * NBUCK + b] : 0;
        s += v;
    }
    __shared__ int ss[256];
    ss[t] = s;
    __syncthreads();
    for (int off = 1; off < 256; off <<= 1) {
        int u = (t >= off) ? ss[t - off] : 0;
        __syncthreads();
        ss[t] += u;
        __syncthreads();
    }
    int excl = ss[t] - s;
#pragma unroll
    for (int j = 0; j < 4; ++j) {
        int blk = t * 4 + j;
        if (blk < NTILEBLK) mat[(size_t)blk * NBUCK + b] = excl + cpre[j];
    }
    if (t == 255) bucket_count[b] = ss[255];
}

// ---------------------------------------------------------------------------
// bucket_scan: exclusive scan of 391 bucket counts -> bucket_base
// ---------------------------------------------------------------------------
__global__ __launch_bounds__(512) void bucket_scan_kernel(const int* __restrict__ bucket_count,
                                                          int* __restrict__ bucket_base,
                                                          int* __restrict__ offsets) {
    __shared__ int s[512];
    const int t = threadIdx.x;
    int v = (t < NBUCK) ? bucket_count[t] : 0;
    s[t] = v;
    __syncthreads();
    for (int off = 1; off < 512; off <<= 1) {
        int u = (t >= off) ? s[t - off] : 0;
        __syncthreads();
        s[t] += u;
        __syncthreads();
    }
    if (t < NBUCK) bucket_base[t] = s[t] - v;
    if (t == 0) offsets[N_NODES] = N_EDGES;
}

// ---------------------------------------------------------------------------
// binA: LDS counting-sort per block, coalesced run-contiguous writeout.
// Zero global atomics (run bases precomputed via mat column prefix).
// Record = {src | dstlocal8<<24, a}.
// ---------------------------------------------------------------------------
__global__ __launch_bounds__(256) void binA_kernel(const int* __restrict__ src,
                                                   const int* __restrict__ dst,
                                                   const float* __restrict__ a,
                                                   const int* __restrict__ bucket_base,
                                                   const int* __restrict__ mat,
                                                   int2* __restrict__ temp) {
    __shared__ int lcount[NBUCK];
    __shared__ int lscan[512];
    __shared__ int lgbase[NBUCK];
    __shared__ int2 stage[TILE];
    __shared__ unsigned short sbuck[TILE];

    const int t = threadIdx.x;
    const int base = blockIdx.x * TILE;

    for (int b = t; b < NBUCK; b += 256) lcount[b] = 0;
    __syncthreads();

    // phase 1: count + rank (LDS atomics only, int — native)
    int dv[TILE / 256], rk[TILE / 256];
#pragma unroll
    for (int k = 0; k < TILE / 256; ++k) {
        int e = base + k * 256 + t;
        dv[k] = 0; rk[k] = 0;
        if (e < N_EDGES) {
            int d = dst[e];
            dv[k] = d;
            rk[k] = atomicAdd(&lcount[((unsigned)d) >> BUCKET_SHIFT], 1);
        }
    }
    __syncthreads();

    // phase 2a: inclusive scan of counts
    lscan[t]       = (t < NBUCK) ? lcount[t] : 0;
    lscan[t + 256] = (t + 256 < NBUCK) ? lcount[t + 256] : 0;
    __syncthreads();
    for (int off = 1; off < 512; off <<= 1) {
        int u0 = (t >= off) ? lscan[t - off] : 0;
        int u1 = ((t + 256) >= off) ? lscan[t + 256 - off] : 0;
        __syncthreads();
        lscan[t] += u0;
        lscan[t + 256] += u1;
        __syncthreads();
    }
    // phase 2b: run bases from precomputed column prefix (no atomics)
    {
        const int* row = mat + (size_t)blockIdx.x * NBUCK;
        for (int b = t; b < NBUCK; b += 256) {
            int excl = lscan[b] - lcount[b];
            lgbase[b] = bucket_base[b] + row[b] - excl;
        }
    }
    __syncthreads();

    // phase 3: scatter into LDS, sorted by bucket
#pragma unroll
    for (int k = 0; k < TILE / 256; ++k) {
        int e = base + k * 256 + t;
        if (e < N_EDGES) {
            int d = dv[k];
            int b = ((unsigned)d) >> BUCKET_SHIFT;
            int slot = (lscan[b] - lcount[b]) + rk[k];
            stage[slot] = make_int2(src[e] | ((d & 255) << 24), __float_as_int(a[e]));
            sbuck[slot] = (unsigned short)b;
        }
    }
    __syncthreads();

    // phase 4: coalesced run-contiguous writeout
    const int cntT = min(TILE, N_EDGES - base);
    for (int i = t; i < cntT; i += 256) {
        temp[lgbase[sbuck[i]] + i] = stage[i];
    }
}

// ---------------------------------------------------------------------------
// binB: one block per bucket -> CSR offsets + node-sorted edge placement
// (L2-local 64 KB window)
// ---------------------------------------------------------------------------
__global__ __launch_bounds__(256) void binB_kernel(const int2* __restrict__ temp,
                                                   const int* __restrict__ bucket_base,
                                                   const int* __restrict__ bucket_count,
                                                   int* __restrict__ offsets,
                                                   int2* __restrict__ edges) {
    const int b = blockIdx.x;
    const int node0 = b << BUCKET_SHIFT;
    const int nodes = min(256, N_NODES - node0);
    const int beg = bucket_base[b];
    const int cnt = bucket_count[b];
    const int t = threadIdx.x;

    __shared__ int ncount[256];
    __shared__ int ssc[256];
    __shared__ int ncur[256];
    ncount[t] = 0;
    __syncthreads();
    for (int i = t; i < cnt; i += 256) {
        unsigned w0 = (unsigned)temp[beg + i].x;
        atomicAdd(&ncount[w0 >> 24], 1);
    }
    __syncthreads();
    int v = ncount[t];
    ssc[t] = v;
    __syncthreads();
    for (int off = 1; off < 256; off <<= 1) {
        int u = (t >= off) ? ssc[t - off] : 0;
        __syncthreads();
        ssc[t] += u;
        __syncthreads();
    }
    int excl = ssc[t] - v;
    if (t < nodes) offsets[node0 + t] = beg + excl;
    ncur[t] = beg + excl;
    __syncthreads();
    for (int i = t; i < cnt; i += 256) {
        int2 r = temp[beg + i];
        int loc = ((unsigned)r.x) >> 24;
        int pos = atomicAdd(&ncur[loc], 1);
        edges[pos] = make_int2(r.x & 0xFFFFFF, r.y);
    }
}

// ---------------------------------------------------------------------------
// gather: hn_bf[v] = bf16( sum a_e * h_bf[u] )   (8-deep ILP)
// Half-wave (32 lanes) per node; lane covers 2 cols. No LDS, 12500 blocks.
// ---------------------------------------------------------------------------
__global__ __launch_bounds__(256) void gather_kernel(
        const unsigned short* __restrict__ h_bf,
        const int2* __restrict__ edges,
        const int* __restrict__ offsets,
        unsigned short* __restrict__ hn_bf) {
    const int lane   = threadIdx.x & 63;
    const int half   = lane >> 5;
    const int sub    = lane & 31;
    const int waveid = (blockIdx.x * blockDim.x + threadIdx.x) >> 6;
    const int node   = waveid * 2 + half;
    if (node >= N_NODES) return;

    const int beg = offsets[node];
    const int end = offsets[node + 1];
    const int c2 = sub * 2;

    float al0=0.f,al1=0.f,al2=0.f,al3=0.f,al4=0.f,al5=0.f,al6=0.f,al7=0.f;
    float ah0=0.f,ah1=0.f,ah2=0.f,ah3=0.f,ah4=0.f,ah5=0.f,ah6=0.f,ah7=0.f;
    int i = beg;
    for (; i + 8 <= end; i += 8) {
        int4 q0 = *(const int4*)&edges[i + 0];   // e0,e1
        int4 q1 = *(const int4*)&edges[i + 2];   // e2,e3
        int4 q2 = *(const int4*)&edges[i + 4];   // e4,e5
        int4 q3 = *(const int4*)&edges[i + 6];   // e6,e7
        unsigned p0 = *(const unsigned*)&h_bf[(size_t)q0.x * DIM + c2];
        unsigned p1 = *(const unsigned*)&h_bf[(size_t)q0.z * DIM + c2];
        unsigned p2 = *(const unsigned*)&h_bf[(size_t)q1.x * DIM + c2];
        unsigned p3 = *(const unsigned*)&h_bf[(size_t)q1.z * DIM + c2];
        unsigned p4 = *(const unsigned*)&h_bf[(size_t)q2.x * DIM + c2];
        unsigned p5 = *(const unsigned*)&h_bf[(size_t)q2.z * DIM + c2];
        unsigned p6 = *(const unsigned*)&h_bf[(size_t)q3.x * DIM + c2];
        unsigned p7 = *(const unsigned*)&h_bf[(size_t)q3.z * DIM + c2];
        float w0 = __int_as_float(q0.y), w1 = __int_as_float(q0.w);
        float w2 = __int_as_float(q1.y), w3 = __int_as_float(q1.w);
        float w4 = __int_as_float(q2.y), w5 = __int_as_float(q2.w);
        float w6 = __int_as_float(q3.y), w7 = __int_as_float(q3.w);
        al0 = fmaf(w0, bflo(p0), al0);  ah0 = fmaf(w0, bfhi(p0), ah0);
        al1 = fmaf(w1, bflo(p1), al1);  ah1 = fmaf(w1, bfhi(p1), ah1);
        al2 = fmaf(w2, bflo(p2), al2);  ah2 = fmaf(w2, bfhi(p2), ah2);
        al3 = fmaf(w3, bflo(p3), al3);  ah3 = fmaf(w3, bfhi(p3), ah3);
        al4 = fmaf(w4, bflo(p4), al4);  ah4 = fmaf(w4, bfhi(p4), ah4);
        al5 = fmaf(w5, bflo(p5), al5);  ah5 = fmaf(w5, bfhi(p5), ah5);
        al6 = fmaf(w6, bflo(p6), al6);  ah6 = fmaf(w6, bfhi(p6), ah6);
        al7 = fmaf(w7, bflo(p7), al7);  ah7 = fmaf(w7, bfhi(p7), ah7);
    }
    for (; i < end; ++i) {
        int2 e = edges[i];
        unsigned p = *(const unsigned*)&h_bf[(size_t)e.x * DIM + c2];
        float w = __int_as_float(e.y);
        al0 = fmaf(w, bflo(p), al0);
        ah0 = fmaf(w, bfhi(p), ah0);
    }
    float lo = ((al0 + al1) + (al2 + al3)) + ((al4 + al5) + (al6 + al7));
    float hi = ((ah0 + ah1) + (ah2 + ah3)) + ((ah4 + ah5) + (ah6 + ah7));

    *(unsigned*)&hn_bf[(size_t)node * DIM + c2] = pkbf(lo, hi);
}

// ---------------------------------------------------------------------------
// update (MFMA, no LDS): t1/t2 A-fragments built IN REGISTERS from
// h_bf + hn_bf (same b128 fragment bytes), 16 MFMAs, leaky epilogue.
// Writes h_bf in place (each wave reads its own 16 rows before writing them)
// and out. No fp32 h, no t1g/t2g round-trip.
// ---------------------------------------------------------------------------
__global__ __launch_bounds__(256) void update_kernel(
        const unsigned short* __restrict__ hn_bf,
        unsigned short* h_bf,                       // read h^l rows, write h^{l+1}
        const unsigned short* __restrict__ wfrag,
        const float* __restrict__ b1,
        const float* __restrict__ b2,
        float* __restrict__ out,
        int out_col_base) {
    const int t    = threadIdx.x;
    const int lane = t & 63;
    const int wid  = t >> 6;
    const int node0 = blockIdx.x * 64;

    // W fragments + biases (L2-hot)
    short8 w1f[2][4], w2f[2][4];
#pragma unroll
    for (int kt = 0; kt < 2; ++kt)
#pragma unroll
        for (int ct = 0; ct < 4; ++ct) {
            w1f[kt][ct] = *(const short8*)(wfrag + (((0 * 2 + kt) * 4 + ct) * 64 + lane) * 8);
            w2f[kt][ct] = *(const short8*)(wfrag + (((1 * 2 + kt) * 4 + ct) * 64 + lane) * 8);
        }
    float bb1[4], bb2[4];
#pragma unroll
    for (int ct = 0; ct < 4; ++ct) {
        bb1[ct] = b1[ct * 16 + (lane & 15)];
        bb2[ct] = b2[ct * 16 + (lane & 15)];
    }

    // A-fragments: load h & hn fragment bytes, combine elementwise in regs
    const int arow = node0 + wid * 16 + (lane & 15);
    const size_t abase = (size_t)arow * DIM + ((lane >> 4) << 3);
    short8 a1[2], a2[2];
#pragma unroll
    for (int kt = 0; kt < 2; ++kt) {
        short8 hf = *(const short8*)&h_bf[abase + kt * 32];
        short8 nf = *(const short8*)&hn_bf[abase + kt * 32];
        short8 t1v, t2v;
#pragma unroll
        for (int j = 0; j < 8; ++j) {
            float fh = bfu((unsigned short)hf[j]);
            float fn = bfu((unsigned short)nf[j]);
            t1v[j] = (short)f2bf(fh + fn);
            t2v[j] = (short)f2bf(fh * fn);
        }
        a1[kt] = t1v;
        a2[kt] = t2v;
    }

    f32x4 acc1[4], acc2[4];
#pragma unroll
    for (int ct = 0; ct < 4; ++ct) {
        acc1[ct] = (f32x4){bb1[ct], bb1[ct], bb1[ct], bb1[ct]};
        acc2[ct] = (f32x4){bb2[ct], bb2[ct], bb2[ct], bb2[ct]};
    }
#pragma unroll
    for (int ct = 0; ct < 4; ++ct) {
        acc1[ct] = __builtin_amdgcn_mfma_f32_16x16x32_bf16(a1[0], w1f[0][ct], acc1[ct], 0, 0, 0);
        acc1[ct] = __builtin_amdgcn_mfma_f32_16x16x32_bf16(a1[1], w1f[1][ct], acc1[ct], 0, 0, 0);
        acc2[ct] = __builtin_amdgcn_mfma_f32_16x16x32_bf16(a2[0], w2f[0][ct], acc2[ct], 0, 0, 0);
        acc2[ct] = __builtin_amdgcn_mfma_f32_16x16x32_bf16(a2[1], w2f[1][ct], acc2[ct], 0, 0, 0);
    }

    // epilogue: leaky + add, write h_bf / out
#pragma unroll
    for (int ct = 0; ct < 4; ++ct) {
        const int col = ct * 16 + (lane & 15);
#pragma unroll
        for (int r = 0; r < 4; ++r) {
            const int grow = node0 + wid * 16 + (lane >> 4) * 4 + r;
            if (grow < N_NODES) {
                float v1 = acc1[ct][r]; v1 = v1 > 0.f ? v1 : 0.01f * v1;
                float v2 = acc2[ct][r]; v2 = v2 > 0.f ? v2 : 0.01f * v2;
                float hnew = v1 + v2;
                h_bf[(size_t)grow * DIM + col] = f2bf(hnew);
                out[(size_t)grow * OUT_COLS + out_col_base + col] = hnew;
            }
        }
    }
}

// ---------------------------------------------------------------------------
extern "C" void kernel_launch(void* const* d_in, const int* in_sizes, int n_in,
                              void* d_out, int out_size, void* d_ws, size_t ws_size,
                              hipStream_t stream) {
    const float* x   = (const float*)d_in[0];
    const float* a   = (const float*)d_in[1];
    const float* W1s = (const float*)d_in[2];
    const float* b1s = (const float*)d_in[3];
    const float* W2s = (const float*)d_in[4];
    const float* b2s = (const float*)d_in[5];
    const int*   src = (const int*)d_in[6];
    const int*   dst = (const int*)d_in[7];
    float* out = (float*)d_out;

    // workspace layout
    int2* edges = (int2*)d_ws;                                         // [E] node-sorted CSR
    int2* temp  = edges + (size_t)N_EDGES;                             // [E] binA staging
    unsigned short* h_bf  = (unsigned short*)(temp + (size_t)N_EDGES); // [PAD,64] bf16 state
    unsigned short* hn_bf = h_bf + (size_t)PAD_NODES * DIM;            // [PAD,64] bf16 hn
    int* offsets = (int*)(hn_bf + (size_t)PAD_NODES * DIM);            // [N+1]
    int* bucket_count = offsets + N_NODES + 1;                         // [NBUCK]
    int* bucket_base  = bucket_count + NBUCK;                          // [NBUCK]
    uintptr_t p2 = (uintptr_t)(bucket_base + NBUCK);
    p2 = (p2 + 15) & ~(uintptr_t)15;
    unsigned short* wfrag = (unsigned short*)p2;                       // [3*8192] bf16 frags
    uintptr_t p3 = (uintptr_t)(wfrag + 3 * WFRAG_PER_LAYER);
    p3 = (p3 + 15) & ~(uintptr_t)15;
    int* mat = (int*)p3;                                               // [NTILEBLK * NBUCK]

    // h_bf = bf16(x) ; out[:, :64] = x ; pad rows zeroed
    {
        int ptotal = PAD_NODES * DIM / 4;
        init_kernel<<<(ptotal + 255) / 256, 256, 0, stream>>>(x, h_bf, hn_bf, out);
    }

    // pack weight fragments
    wprep_kernel<<<(3 * WFRAG_PER_LAYER + 255) / 256, 256, 0, stream>>>(W1s, W2s, wfrag);

    // CSR build — zero global atomics
    count_kernel<<<NTILEBLK, 256, 0, stream>>>(dst, mat);
    scan2_kernel<<<NBUCK, 256, 0, stream>>>(mat, bucket_count);
    bucket_scan_kernel<<<1, 512, 0, stream>>>(bucket_count, bucket_base, offsets);
    binA_kernel<<<NTILEBLK, 256, 0, stream>>>(src, dst, a, bucket_base, mat, temp);
    binB_kernel<<<NBUCK, 256, 0, stream>>>(temp, bucket_base, bucket_count, offsets, edges);

    // 3 layers: split gather (max parallelism) + short MFMA update, bf16 state
    for (int l = 0; l < 3; ++l) {
        int waves = (N_NODES + 1) / 2;
        int blocks = (waves * 64 + 255) / 256;
        gather_kernel<<<blocks, 256, 0, stream>>>(h_bf, edges, offsets, hn_bf);
        update_kernel<<<NODE_TILES, 256, 0, stream>>>(
            hn_bf, h_bf,
            wfrag + (size_t)l * WFRAG_PER_LAYER,
            b1s + (size_t)l * DIM,
            b2s + (size_t)l * DIM,
            out, (l + 1) * DIM);
    }
}